// Round 2
// baseline (263.477 us; speedup 1.0000x reference)
//
#include <hip/hip_runtime.h>

// FIR bandpass, zero-phase, reflect_limited padding — direct correlation form.
// out[t] = sum_{j=0..412} hr[j] * xe[t+j],  hr[j] = h[412-j],  xe[i] = x_ext[i+206]
// x_ext: [2*x[0]-x[412:0:-1], x, 2*x[-1]-x[-2:-414:-1]]  (len 4824)
//
// One block per (b,c) row. Extended row staged in LDS with an XOR swizzle so the
// stride-16 per-thread float4 window reads are bank-conflict-free. Each thread
// computes 16 contiguous outputs via a 5 x float4 circular register window.

typedef float f4 __attribute__((ext_vector_type(4)));

#define T_LEN   4000
#define N_ROWS  4096
#define XE_WORDS 4544   // multiple of 32 (swizzle block), >= 4520 max read index
#define HR_LEN   420    // 413 taps zero-padded to 420 = 21*5*4

// Swizzle: XOR word-address bits [2..4] with bits [4..6]. Bijective within each
// 32-word block; spreads 8 consecutive stride-16 lanes over all 8 bank-groups.
__device__ __forceinline__ int swz(int w) { return w ^ ((w >> 2) & 0x1C); }

__global__ void fir_rows_kernel(const float* __restrict__ x,
                                const float* __restrict__ h,
                                float* __restrict__ out) {
    __shared__ __align__(16) float sxe[XE_WORDS];
    __shared__ __align__(16) float shr[HR_LEN];

    const int row = blockIdx.x;
    const int tid = threadIdx.x;
    const float* __restrict__ xr = x + row * T_LEN;

    // Reversed, zero-padded taps
    for (int j = tid; j < HR_LEN; j += 256)
        shr[j] = (j <= 412) ? h[412 - j] : 0.0f;

    // Extended signal window xe[i] = x_ext[i+206], swizzled store
    const float x0 = xr[0];
    const float xN = xr[T_LEN - 1];
    for (int i = tid; i < XE_WORDS; i += 256) {
        const int pos = i + 206;           // index into conceptual x_ext
        float v;
        if (pos < 412)          v = 2.0f * x0 - xr[412 - pos];
        else if (pos < 4412)    v = xr[pos - 412];
        else                    v = 2.0f * xN - xr[8410 - pos];
        sxe[swz(i)] = v;
    }
    __syncthreads();

    const int t0 = tid * 16;               // 16 contiguous outputs per thread

    float acc[16];
    #pragma unroll
    for (int r = 0; r < 16; ++r) acc[r] = 0.0f;

    // 5-group circular register window: covers xe indices [t0+j .. t0+j+19]
    f4 g[5];
    #pragma unroll
    for (int q = 0; q < 5; ++q)
        g[q] = *(const f4*)(sxe + swz(t0 + 4 * q));

    int jb = 0;
    #pragma unroll 1
    for (int it = 0; it < 21; ++it) {
        #pragma unroll
        for (int ph = 0; ph < 5; ++ph) {
            const int j = jb + 4 * ph;
            const f4 h4 = *(const f4*)(shr + j);     // uniform -> LDS broadcast
            #pragma unroll
            for (int jj = 0; jj < 4; ++jj) {
                #pragma unroll
                for (int r = 0; r < 16; ++r) {
                    const int m = r + jj;            // window offset 0..18
                    acc[r] = __builtin_fmaf(g[(ph + (m >> 2)) % 5][m & 3],
                                            h4[jj], acc[r]);
                }
            }
            // slide window: overwrite oldest group with next 4 words
            g[ph] = *(const f4*)(sxe + swz(t0 + j + 20));
        }
        jb += 20;
    }

    if (t0 < T_LEN) {
        f4* op = (f4*)(out + row * T_LEN + t0);
        #pragma unroll
        for (int q = 0; q < 4; ++q) {
            f4 v;
            v[0] = acc[4 * q + 0];
            v[1] = acc[4 * q + 1];
            v[2] = acc[4 * q + 2];
            v[3] = acc[4 * q + 3];
            op[q] = v;
        }
    }
}

extern "C" void kernel_launch(void* const* d_in, const int* in_sizes, int n_in,
                              void* d_out, int out_size, void* d_ws, size_t ws_size,
                              hipStream_t stream) {
    const float* x = (const float*)d_in[0];   // [64,64,4000] f32
    const float* h = (const float*)d_in[1];   // [413] f32
    float* out = (float*)d_out;               // [64,64,4000] f32
    fir_rows_kernel<<<dim3(N_ROWS), dim3(256), 0, stream>>>(x, h, out);
}

// Round 3
// 172.729 us; speedup vs baseline: 1.5254x; 1.5254x over previous
//
#include <hip/hip_runtime.h>

// FIR bandpass as per-row MFMA GEMM (shifted-filter trick):
//   out[16u+v] = sum_k xe[16u+k] * Bm[k][v],  Bm[k][v] = hr[k-v] (0 outside [0,412])
//   hr[j] = h[412-j],  xe[i] = x_ext[i+206]  (reflect_limited pad)
// x split as x = hi + lo (two bf16), taps in bf16; fp32 MFMA accumulate.
// A-frags from LDS (quad-preserving XOR swizzle, conflict-free b64 reads);
// all 14 B-frags built once into 56 VGPRs.

typedef short  s8v  __attribute__((ext_vector_type(8)));
typedef short  s4v  __attribute__((ext_vector_type(4)));
typedef float  f4v  __attribute__((ext_vector_type(4)));

#define T_LEN  4000
#define N_ROWS 4096
#define XE_N   4544           // staged bf16 elements (max read idx 4527)
#define XE_W   (XE_N / 2)     // 2272 packed u32 words
#define K_LEN  448            // padded taps: 14 chunks of 32
#define NCH    14

__device__ __forceinline__ unsigned short f2bf(float x) {
    unsigned u = __float_as_uint(x);
    u += 0x7FFFu + ((u >> 16) & 1u);          // round-to-nearest-even
    return (unsigned short)(u >> 16);
}
__device__ __forceinline__ float bf2f(unsigned short b) {
    return __uint_as_float(((unsigned)b) << 16);
}
// Quad-preserving LDS swizzle on u32-word index: XOR bits 5..6 into bits 1..2.
// Per 16-lane phase of the stride-8-word A-reads this maps the 16 lanes onto
// 16 distinct bank-pairs (all 32 banks) -> conflict-free ds_read_b64.
__device__ __forceinline__ int swzw(int w) { return w ^ ((w >> 4) & 6); }

__global__ __launch_bounds__(256, 4)
void fir_mfma_kernel(const float* __restrict__ x,
                     const float* __restrict__ h,
                     float* __restrict__ out) {
    __shared__ unsigned int   sxh[XE_W];      // hi bf16 pairs (swizzled words)
    __shared__ unsigned int   sxl[XE_W];      // lo bf16 pairs (swizzled words)
    __shared__ unsigned short shr[K_LEN];     // reversed taps, bf16, linear

    const int row = blockIdx.x;
    const int tid = threadIdx.x;
    const float* __restrict__ xr = x + row * T_LEN;

    // taps: shr[d] = bf16(h[412-d]), zero-padded to 448
    for (int j = tid; j < K_LEN; j += 256)
        shr[j] = (j <= 412) ? f2bf(h[412 - j]) : (unsigned short)0;

    const float x0 = xr[0];
    const float xN = xr[T_LEN - 1];

    // stage xe[i] = x_ext[i+206] as packed hi/lo bf16 pairs, swizzled
    for (int w = tid; w < XE_W; w += 256) {
        const int p0 = 2 * w + 206;           // x_ext position of even element
        float v0, v1;
        if (p0 >= 412 && p0 + 1 < 4412) {     // interior: vector load
            const float2 xx = *(const float2*)(xr + (p0 - 412));
            v0 = xx.x; v1 = xx.y;
        } else {
            v0 = (p0 < 412)  ? 2.0f * x0 - xr[412 - p0]
               : (p0 < 4412) ? xr[p0 - 412]
                             : 2.0f * xN - xr[8410 - p0];
            const int p1 = p0 + 1;
            v1 = (p1 < 412)  ? 2.0f * x0 - xr[412 - p1]
               : (p1 < 4412) ? xr[p1 - 412]
                             : 2.0f * xN - xr[8410 - p1];
        }
        const unsigned short h0 = f2bf(v0), h1 = f2bf(v1);
        const unsigned short l0 = f2bf(v0 - bf2f(h0));
        const unsigned short l1 = f2bf(v1 - bf2f(h1));
        const int ws = swzw(w);
        sxh[ws] = (unsigned)h0 | ((unsigned)h1 << 16);
        sxl[ws] = (unsigned)l0 | ((unsigned)l1 << 16);
    }
    __syncthreads();

    const int l = tid & 63;
    const int g = l >> 4;        // k-group within fragment
    const int m = l & 15;        // A-row / B-col / D-col
    const int wave = tid >> 6;

    // Build all 14 B-fragments once (identical across the 4 waves).
    // frag elem e -> k = 32c + 4g + (e&3) + 16(e>>2); B[k][v=m] = shr[k-m].
    s8v bfr[NCH];
    #pragma unroll
    for (int c = 0; c < NCH; ++c) {
        #pragma unroll
        for (int e = 0; e < 8; ++e) {
            const int k = 32 * c + 4 * g + (e & 3) + 16 * (e >> 2);
            const int d = k - m;
            bfr[c][e] = (d >= 0 && d < K_LEN) ? (short)shr[d] : (short)0;
        }
    }

    const unsigned short* sxhp = (const unsigned short*)sxh;
    const unsigned short* sxlp = (const unsigned short*)sxl;
    const int lbase = 8 * m + 2 * g;   // lane part of A word address

    float* __restrict__ orow = out + row * T_LEN;

    for (int ii = 0; ii < 4; ++ii) {
        const int i = wave + 4 * ii;   // M-tile 0..15 (u = 16i + 4g + reg)
        f4v acc_h = {0.f, 0.f, 0.f, 0.f};
        f4v acc_l = {0.f, 0.f, 0.f, 0.f};
        const int ibase = lbase + 128 * i;
        #pragma unroll
        for (int c = 0; c < NCH; ++c) {
            const int w0 = ibase + 16 * c;       // word of A elems k..k+3
            const int a0 = swzw(w0);
            const int a1 = swzw(w0 + 8);         // word of A elems k+16..k+19
            const s4v ah_lo = *(const s4v*)(sxhp + 2 * a0);
            const s4v ah_hi = *(const s4v*)(sxhp + 2 * a1);
            const s4v al_lo = *(const s4v*)(sxlp + 2 * a0);
            const s4v al_hi = *(const s4v*)(sxlp + 2 * a1);
            const s8v ah = __builtin_shufflevector(ah_lo, ah_hi, 0,1,2,3,4,5,6,7);
            const s8v al = __builtin_shufflevector(al_lo, al_hi, 0,1,2,3,4,5,6,7);
            acc_h = __builtin_amdgcn_mfma_f32_16x16x32_bf16(ah, bfr[c], acc_h, 0, 0, 0);
            acc_l = __builtin_amdgcn_mfma_f32_16x16x32_bf16(al, bfr[c], acc_l, 0, 0, 0);
        }
        // D: col = lane&15 (=v), row-in-tile = 4*(lane>>4) + reg
        const int tb = 256 * i + 64 * g + m;
        #pragma unroll
        for (int r = 0; r < 4; ++r) {
            const int t = tb + 16 * r;
            if (t < T_LEN) orow[t] = acc_h[r] + acc_l[r];
        }
    }
}

extern "C" void kernel_launch(void* const* d_in, const int* in_sizes, int n_in,
                              void* d_out, int out_size, void* d_ws, size_t ws_size,
                              hipStream_t stream) {
    const float* x = (const float*)d_in[0];   // [64,64,4000] f32
    const float* h = (const float*)d_in[1];   // [413] f32
    float* out = (float*)d_out;               // [64,64,4000] f32
    fir_mfma_kernel<<<dim3(N_ROWS), dim3(256), 0, stream>>>(x, h, out);
}

// Round 4
// 131.394 us; speedup vs baseline: 2.0052x; 1.3146x over previous
//
#include <hip/hip_runtime.h>

// FIR bandpass as per-row MFMA GEMM, single-bf16, permuted-K fragments.
//   out[16u+v] = sum_k xe[16u+k] * B[k][v],  B[k][v] = hr[k-v] (banded, K=448)
//   hr[j] = h[412-j],  xe[i] = x_ext[i+206]  (reflect_limited padding)
// Permuted-K: logical k = 32c + 8*grp + e in both A and B fragment slots
// (bijection of the hw k-slots -> exact). A-frag = 8 contiguous bf16 in LDS
// -> one conflict-free ds_read_b128, linear layout, offsets all immediates.
// B fragment table (14 KiB) precomputed by a 1-block kernel into d_ws and
// broadcast-loaded from L2/L3 by every wave. Waves stream 38 A-chunks with
// prefetch depth 6; consecutive M-tiles reuse 6/14 chunks from registers.

typedef short  s8v __attribute__((ext_vector_type(8)));
typedef float  f4v __attribute__((ext_vector_type(4)));

#define T_LEN  4000
#define N_ROWS 4096
#define XE_W   2272      // u32 words of packed bf16 pairs (4544 elems, max idx 4527)
#define NCH    14        // K = 448 = 14 chunks of 32
#define NQ     38        // streamed chunks per wave: 4 tiles, stride 8, +14
#define PF     6         // A prefetch distance (chunks)

__device__ __forceinline__ unsigned short f2bf(float x) {
    unsigned u = __float_as_uint(x);
    u += 0x7FFFu + ((u >> 16) & 1u);     // round-to-nearest-even
    return (unsigned short)(u >> 16);
}

// ---- pre-kernel: B fragment table (NCH*64 lanes * 16 B = 14336 B) in ws ----
// lane l = (grp = l>>4, n = l&15); elem e of chunk c holds logical k = 32c+8*grp+e:
//   val = hr[k - n] = h[412 - (k-n)] if 0 <= k-n <= 412 else 0
__global__ void build_btab(const float* __restrict__ h, unsigned* __restrict__ ws) {
    for (int fl = threadIdx.x; fl < NCH * 64; fl += 256) {
        const int c = fl >> 6, l = fl & 63;
        const int kb = 32 * c + 8 * (l >> 4) - (l & 15);   // d for e=0
        unsigned w[4];
        #pragma unroll
        for (int j = 0; j < 4; ++j) {
            const int d0 = kb + 2 * j, d1 = kb + 2 * j + 1;
            const unsigned short lo = (d0 >= 0 && d0 <= 412) ? f2bf(h[412 - d0]) : 0;
            const unsigned short hi = (d1 >= 0 && d1 <= 412) ? f2bf(h[412 - d1]) : 0;
            w[j] = (unsigned)lo | ((unsigned)hi << 16);
        }
        *(uint4*)(ws + 4 * fl) = make_uint4(w[0], w[1], w[2], w[3]);
    }
}

// ------------------------------- main kernel --------------------------------
__global__ __launch_bounds__(256, 3)
void fir_mfma2(const float* __restrict__ x, const unsigned* __restrict__ btab,
               float* __restrict__ out) {
    __shared__ unsigned sxe[XE_W];       // linear packed bf16 pairs

    const int row = blockIdx.x, tid = threadIdx.x;
    const int l = tid & 63, wave = tid >> 6;
    const float* __restrict__ xr = x + row * T_LEN;

    // B fragments: 14 coalesced b128 loads from the precomputed table
    s8v bfr[NCH];
    #pragma unroll
    for (int c = 0; c < NCH; ++c)
        bfr[c] = *(const s8v*)(btab + 4 * (64 * c + l));

    // stage xe[i] = x_ext[i+206] as packed bf16 pairs (single precision level)
    const float x0 = xr[0], xN = xr[T_LEN - 1];
    #pragma unroll
    for (int it = 0; it < 9; ++it) {
        const int w = tid + 256 * it;
        if (w < XE_W) {
            const int p0 = 2 * w + 206;            // x_ext position, even
            float v0, v1;
            if (p0 >= 412 && p0 + 1 < 4412) {      // interior fast path
                const float2 xx = *(const float2*)(xr + (p0 - 412));
                v0 = xx.x; v1 = xx.y;
            } else {
                v0 = (p0 < 412)  ? 2.0f * x0 - xr[412 - p0]
                   : (p0 < 4412) ? xr[p0 - 412]
                                 : 2.0f * xN - xr[8410 - p0];
                const int p1 = p0 + 1;
                v1 = (p1 < 412)  ? 2.0f * x0 - xr[412 - p1]
                   : (p1 < 4412) ? xr[p1 - 412]
                                 : 2.0f * xN - xr[8410 - p1];
            }
            sxe[w] = (unsigned)f2bf(v0) | ((unsigned)f2bf(v1) << 16);
        }
    }
    __syncthreads();

    const int m = l & 15, g = l >> 4;
    // chunk-q A read: 8 contiguous bf16 at elem (1024*wave + 32q + 16m + 8g)
    const char* ap = (const char*)sxe + (2048 * wave + 32 * m + 16 * g);

    f4v acc[4] = {{0.f,0.f,0.f,0.f}, {0.f,0.f,0.f,0.f},
                  {0.f,0.f,0.f,0.f}, {0.f,0.f,0.f,0.f}};
    s8v A[NCH];
    float* __restrict__ orow = out + row * T_LEN;
    const int tb0 = 1024 * wave + 64 * g + m;      // store base (+256*ii+16*r)

    #pragma unroll
    for (int q = 0; q < PF; ++q)
        A[q] = *(const s8v*)(ap + 64 * q);

    #pragma unroll
    for (int q = 0; q < NQ; ++q) {
        if (q + PF < NQ)
            A[(q + PF) % NCH] = *(const s8v*)(ap + 64 * (q + PF));
        #pragma unroll
        for (int ii = 0; ii < 4; ++ii) {
            if (q >= 8 * ii && q < 8 * ii + NCH)   // folded at compile time
                acc[ii] = __builtin_amdgcn_mfma_f32_16x16x32_bf16(
                              A[q % NCH], bfr[q - 8 * ii], acc[ii], 0, 0, 0);
            if (q == 8 * ii + NCH - 1) {           // tile ii complete -> store
                const int tb = tb0 + 256 * ii;
                #pragma unroll
                for (int r = 0; r < 4; ++r) {
                    const int t = tb + 16 * r;
                    if (t < T_LEN) orow[t] = acc[ii][r];
                }
            }
        }
    }
}

extern "C" void kernel_launch(void* const* d_in, const int* in_sizes, int n_in,
                              void* d_out, int out_size, void* d_ws, size_t ws_size,
                              hipStream_t stream) {
    const float* x = (const float*)d_in[0];   // [64,64,4000] f32
    const float* h = (const float*)d_in[1];   // [413] f32
    float* out = (float*)d_out;               // [64,64,4000] f32
    unsigned* btab = (unsigned*)d_ws;         // 14336 B scratch
    build_btab<<<dim3(1), dim3(256), 0, stream>>>(h, btab);
    fir_mfma2<<<dim3(N_ROWS), dim3(256), 0, stream>>>(x, btab, (float*)out);
}